// Round 1
// 1127.277 us; speedup vs baseline: 1.1074x; 1.1074x over previous
//
#include <hip/hip_runtime.h>
#include <math.h>

// QPLayer: batched primal-dual IPM, Q=0, G=-I (LP). f64 inputs DELIVERED AS F32
// (established round 8). Schur complement S = A diag(s/z) A^T (40x40), solved
// with COMPLETE-DIAGONAL-PIVOTED LDL^T (greedy max pivot; load-bearing), lane i
// owns row i of S in registers.
// ROUND 19 (latency-overlap round; kernel is 1-wave/SIMD dependency-bound,
// VALUBusy 24.7%):
//  * P3 SOFTWARE-PIPELINED: next-step argmax + pivot readlane + f64 divide are
//    computed from the incrementally-updated diag selector BEFORE the rank-1
//    j-loop, so the serial DPP/divide chain overlaps 40 independent FMAs.
//    Pivot row double-buffered in two DISTINCT LDS arrays (SrowA/SrowB, via
//    macro binding) so LDS alias analysis stays exact; next pivot row is
//    staged by lane ktn right after the rank-1 updates it.
//  * P4 COLUMN-SWEEP: replaces 40 serial wave_sum_f64 ladders. Lane tau
//    accumulates acc_tau = sum_{t>tau} Lm[tau][kt_t]*x_t (no masking needed:
//    eliminated/dropped lanes stored Lm=0). LmT prefetched into dead Sreg via
//    40 independent ds_reads (addresses from kk_own readlanes); rhs gathered
//    once via ds_bpermute(fy, kk_own); per-step chain = readlane -> fma.
//    Final scatter to row-indexing via ds_permute (pivots form a bijection of
//    [0,40); lanes >=40 self-push junk that is never consumed).
//  * P2 also stores transposed tiles -> S row load is 40 straight ds_reads
//    (removes 40 dual reads + 80 selects per iter). Matvecs use 4 independent
//    accumulators (break the 8-cycle f64 FMA latency chain).
// One wave per batch element; 1024 waves = 4/CU (structural). LDS 36.2 KB ->
// 4 blocks/CU. 4 syncthreads/iter (single-wave workgroup: barriers are ~free,
// kept as memory-ordering guards).

#define NXV   64
#define MEQ   40
#define NITER 25
#define SIGMA_C 0.1
#define FTB_C   0.99
#define SA 65    // LDS row stride for A (doubles)
#define SS 41    // LDS row stride for S staging / Lm store (doubles)
#define PIV_DROP_REL 1e-12

union DU { double d; int i[2]; unsigned u[2]; };

__device__ __forceinline__ double readlane_f64(double v, int lane) {
    DU a; a.d = v; DU r;
    r.i[0] = __builtin_amdgcn_readlane(a.i[0], lane);
    r.i[1] = __builtin_amdgcn_readlane(a.i[1], lane);
    return r.d;
}

// DPP wave64 reduction ladders (verified bit-exact rounds 16/17).
template<int CTRL>
__device__ __forceinline__ double dpp_add_step(double v) {
    DU a; a.d = v; DU b;
    b.i[0] = __builtin_amdgcn_update_dpp(0, a.i[0], CTRL, 0xf, 0xf, true);
    b.i[1] = __builtin_amdgcn_update_dpp(0, a.i[1], CTRL, 0xf, 0xf, true);
    return v + b.d;
}
__device__ __forceinline__ double wave_sum_f64(double v) {
    v = dpp_add_step<0x111>(v); v = dpp_add_step<0x112>(v);
    v = dpp_add_step<0x114>(v); v = dpp_add_step<0x118>(v);
    v = dpp_add_step<0x142>(v); v = dpp_add_step<0x143>(v);
    return readlane_f64(v, 63);
}
template<int CTRL>
__device__ __forceinline__ double dpp_min_step(double v) {   // identity +inf
    DU a; a.d = v; DU b;
    b.i[0] = __builtin_amdgcn_update_dpp(0x00000000, a.i[0], CTRL, 0xf, 0xf, false);
    b.i[1] = __builtin_amdgcn_update_dpp(0x7ff00000, a.i[1], CTRL, 0xf, 0xf, false);
    return fmin(v, b.d);
}
__device__ __forceinline__ double wave_min_f64(double v) {
    v = dpp_min_step<0x111>(v); v = dpp_min_step<0x112>(v);
    v = dpp_min_step<0x114>(v); v = dpp_min_step<0x118>(v);
    v = dpp_min_step<0x142>(v); v = dpp_min_step<0x143>(v);
    return readlane_f64(v, 63);
}
template<int CTRL>
__device__ __forceinline__ double dpp_max_step(double v) {   // identity -inf
    DU a; a.d = v; DU b;
    b.i[0] = __builtin_amdgcn_update_dpp(0x00000000, a.i[0], CTRL, 0xf, 0xf, false);
    b.i[1] = __builtin_amdgcn_update_dpp((int)0xfff00000u, a.i[1], CTRL, 0xf, 0xf, false);
    return fmax(v, b.d);
}
__device__ __forceinline__ double wave_max_f64(double v) {
    v = dpp_max_step<0x111>(v); v = dpp_max_step<0x112>(v);
    v = dpp_max_step<0x114>(v); v = dpp_max_step<0x118>(v);
    v = dpp_max_step<0x142>(v); v = dpp_max_step<0x143>(v);
    return readlane_f64(v, 63);
}
template<int CTRL>
__device__ __forceinline__ unsigned dpp_maxu_step(unsigned v) {
    unsigned m = (unsigned)__builtin_amdgcn_update_dpp(0, (int)v, CTRL, 0xf, 0xf, true);
    return v > m ? v : m;
}
__device__ __forceinline__ unsigned wave_max_u32(unsigned v) {
    v = dpp_maxu_step<0x111>(v); v = dpp_maxu_step<0x112>(v);
    v = dpp_maxu_step<0x114>(v); v = dpp_maxu_step<0x118>(v);
    v = dpp_maxu_step<0x142>(v); v = dpp_maxu_step<0x143>(v);
    return (unsigned)__builtin_amdgcn_readlane((int)v, 63);
}

// One pipelined LDL^T step. Consumes (kt, invP) selected during the PREVIOUS
// step; selects (ktn, invPn) for the next step BEFORE the rank-1 j-loop so the
// DPP argmax + f64 divide overlap the 40 independent FMAs. CUR/NXT are
// distinct LDS arrays (exact alias analysis). Updates diag_r/fy_r/Sreg/
// kk_own/ip_own/kt/invP in the enclosing scope.
#define P3_STEP(T, CUR, NXT)                                                  \
  do {                                                                        \
    const int t_ = (T);                                                       \
    const double col_ = CUR[row];            /* S[kt][i] == S[i][kt] */       \
    const double Lm_ = (diag_r > -1.0e307 && tid != kt) ? col_ * invP : 0.0;  \
    if (tid < MEQ) Sl[t_ * SS + tid] = Lm_;  /* multiplier -> dead LDS */     \
    diag_r -= Lm_ * col_;                    /* selector maintenance */       \
    if (tid == kt) diag_r = -1.0e308;        /* eliminated */                 \
    const double fyk_ = readlane_f64(fy_r, kt);                               \
    fy_r -= Lm_ * fyk_;                      /* unit-L forward solve */       \
    /* next pivot selection: packed-key argmax (overlaps j-loop below) */     \
    DU dd_; dd_.d = diag_r;                                                   \
    const unsigned h_  = dd_.u[1];                                            \
    const unsigned mk_ = (h_ & 0x80000000u) ? ~h_ : (h_ | 0x80000000u);       \
    const unsigned key_ = wave_max_u32((mk_ & 0xFFFFFFC0u) | (unsigned)tid);  \
    const int ktn_ = (int)(key_ & 63u);                                       \
    const double pivn_ = readlane_f64(diag_r, ktn_);                          \
    double ipn_ = 1.0 / pivn_;                                                \
    ipn_ = (pivn_ > thr) ? ipn_ : 0.0;       /* drop noise pivots */          \
    if (tid == t_ + 1 && tid < MEQ) { kk_own = ktn_; ip_own = ipn_; }         \
    _Pragma("unroll")                                                         \
    for (int j = 0; j < MEQ; ++j)            /* rank-1: uniform LDS reads */  \
      Sreg[j] -= Lm_ * CUR[j];                                                \
    if (tid == ktn_) {                       /* stage next pivot row */       \
      _Pragma("unroll")                                                       \
      for (int j = 0; j < MEQ; ++j) NXT[j] = Sreg[j];                         \
    }                                                                         \
    kt = ktn_; invP = ipn_;                                                   \
  } while (0)

__global__ __launch_bounds__(64, 1)
void qp_ipm_kernel(const float* __restrict__ puzzles,
                   const float* __restrict__ Af,
                   const float* __restrict__ lzf,
                   const float* __restrict__ uf,
                   float* __restrict__ out)
{
    __shared__ double Ald[MEQ * SA];                 // 20,800 B
    __shared__ double Sl[MEQ * SS];                  // 13,120 B (S stage, then Lm)
    __shared__ double dl[NXV];                       //    512 B
    __shared__ double vl[NXV];                       //    512 B
    __shared__ __align__(16) double SrowA[MEQ];      //    320 B (pivot row, ping)
    __shared__ __align__(16) double SrowB[MEQ];      //    320 B (pivot row, pong)
    __shared__ double yl[MEQ];                       //    320 B
    __shared__ double Xl[MEQ];                       //    320 B

    const int tid = threadIdx.x;       // 0..63, one wave
    const int b   = blockIdx.x;
    const int row = (tid < MEQ) ? tid : 0;

    for (int e = tid; e < MEQ * NXV; e += 64)
        Ald[(e >> 6) * SA + (e & 63)] = (double)Af[e];
    dl[tid] = exp((double)lzf[tid]);
    if (tid < MEQ) yl[tid] = 0.0;
    __syncthreads();
    double b0 = 0.0, b1 = 0.0, b2 = 0.0, b3 = 0.0;
    #pragma unroll
    for (int i = 0; i < NXV; i += 4) {
        b0 += Ald[row * SA + i + 0] * dl[i + 0];
        b1 += Ald[row * SA + i + 1] * dl[i + 1];
        b2 += Ald[row * SA + i + 2] * dl[i + 2];
        b3 += Ald[row * SA + i + 3] * dl[i + 3];
    }
    const double b_r = (b0 + b1) + (b2 + b3);

    const double u_i = (double)uf[tid];
    const double p_i = -(double)puzzles[b * NXV + tid];
    double x_r = 0.0, s_r = 1.0, z_r = 1.0, y_r = 0.0;

    for (int it = 0; it < NITER; ++it) {
        // ---- P1: residuals/scalings; broadcasts via uniform LDS reads ----
        double at0 = 0.0, at1 = 0.0, at2 = 0.0, at3 = 0.0;
        #pragma unroll
        for (int j = 0; j < MEQ; j += 4) {
            at0 += Ald[(j + 0) * SA + tid] * yl[j + 0];
            at1 += Ald[(j + 1) * SA + tid] * yl[j + 1];
            at2 += Ald[(j + 2) * SA + tid] * yl[j + 2];
            at3 += Ald[(j + 3) * SA + tid] * yl[j + 3];
        }
        const double aty = (at0 + at1) + (at2 + at3);
        const double rd = p_i + aty - z_r;          // Q=0, G^T z = -z
        const double rs = s_r - x_r - u_i;          // -x + s - u
        const double mu = wave_sum_f64(s_r * z_r) * (1.0 / 64.0);
        const double rc = (SIGMA_C * mu - z_r * s_r + z_r * rs) / s_r;
        const double rx = rc - rd;                  // rhs_x
        const double d_r = s_r / z_r;
        const double v_r = d_r * rx + x_r;          // fy = A v - b
        vl[tid] = v_r;                              // same-wave order: write->read ok
        dl[tid] = d_r;

        double f0 = 0.0, f1 = 0.0, f2 = 0.0, f3 = 0.0;
        #pragma unroll
        for (int i = 0; i < NXV; i += 4) {
            f0 += Ald[row * SA + i + 0] * vl[i + 0];
            f1 += Ald[row * SA + i + 1] * vl[i + 1];
            f2 += Ald[row * SA + i + 2] * vl[i + 2];
            f3 += Ald[row * SA + i + 3] * vl[i + 3];
        }
        double fy_r = (f0 + f1) + (f2 + f3) - b_r;
        __syncthreads();                            // barrier 0: dl visible

        // ---- P2: S = A diag(d) A^T, 4x4 lower tiles (lanes<55) -> LDS ----
        // Transposed copy also stored so the S row load is 40 straight reads.
        if (tid < 55) {
            int uu = tid, mb = 0;
            while (uu > mb) { uu -= (mb + 1); ++mb; }
            const int nb = uu;
            double a00=0,a01=0,a02=0,a03=0, a10=0,a11=0,a12=0,a13=0,
                   a20=0,a21=0,a22=0,a23=0, a30=0,a31=0,a32=0,a33=0;
            const double* Am = &Ald[(4 * mb) * SA];
            const double* An = &Ald[(4 * nb) * SA];
            for (int k = 0; k < NXV; ++k) {
                const double dk = dl[k];
                const double r0 = Am[0*SA+k], r1 = Am[1*SA+k], r2 = Am[2*SA+k], r3 = Am[3*SA+k];
                const double c0 = An[0*SA+k]*dk, c1 = An[1*SA+k]*dk, c2 = An[2*SA+k]*dk, c3 = An[3*SA+k]*dk;
                a00 += r0*c0; a01 += r0*c1; a02 += r0*c2; a03 += r0*c3;
                a10 += r1*c0; a11 += r1*c1; a12 += r1*c2; a13 += r1*c3;
                a20 += r2*c0; a21 += r2*c1; a22 += r2*c2; a23 += r2*c3;
                a30 += r3*c0; a31 += r3*c1; a32 += r3*c2; a33 += r3*c3;
            }
            double* Sp = &Sl[(4 * mb) * SS + 4 * nb];
            Sp[0*SS+0]=a00; Sp[0*SS+1]=a01; Sp[0*SS+2]=a02; Sp[0*SS+3]=a03;
            Sp[1*SS+0]=a10; Sp[1*SS+1]=a11; Sp[1*SS+2]=a12; Sp[1*SS+3]=a13;
            Sp[2*SS+0]=a20; Sp[2*SS+1]=a21; Sp[2*SS+2]=a22; Sp[2*SS+3]=a23;
            Sp[3*SS+0]=a30; Sp[3*SS+1]=a31; Sp[3*SS+2]=a32; Sp[3*SS+3]=a33;
            if (mb != nb) {                         // transpose tile
                double* Sq = &Sl[(4 * nb) * SS + 4 * mb];
                Sq[0*SS+0]=a00; Sq[1*SS+0]=a01; Sq[2*SS+0]=a02; Sq[3*SS+0]=a03;
                Sq[0*SS+1]=a10; Sq[1*SS+1]=a11; Sq[2*SS+1]=a12; Sq[3*SS+1]=a13;
                Sq[0*SS+2]=a20; Sq[1*SS+2]=a21; Sq[2*SS+2]=a22; Sq[3*SS+2]=a23;
                Sq[0*SS+3]=a30; Sq[1*SS+3]=a31; Sq[2*SS+3]=a32; Sq[3*SS+3]=a33;
            }
        }
        __syncthreads();   // barrier 1: tiles visible

        // ---- load row tid of S into registers (full row now stored) ----
        double Sreg[MEQ];
        double diag_r;
        if (tid < MEQ) {
            #pragma unroll
            for (int j = 0; j < MEQ; ++j) Sreg[j] = Sl[tid * SS + j];
            diag_r = Sl[tid * SS + tid];
        } else {
            #pragma unroll
            for (int j = 0; j < MEQ; ++j) Sreg[j] = 0.0;
            diag_r = -1.0e308;
        }
        const double dg  = wave_max_f64(diag_r);
        const double thr = dg * PIV_DROP_REL;
        __syncthreads();   // barrier 2: Sl dead -> reuse as Lm store

        // ---- P3: pipelined greedy-max-pivot LDL^T ----
        double ip_own = 0.0;
        int    kk_own = tid;          // lanes >=40 self-push in the P4 scatter
        int    kt;  double invP;
        {   // prologue: select pivot 0, stage its row into SrowA
            DU dd; dd.d = diag_r;
            const unsigned h  = dd.u[1];
            const unsigned mk = (h & 0x80000000u) ? ~h : (h | 0x80000000u);
            const unsigned key = wave_max_u32((mk & 0xFFFFFFC0u) | (unsigned)tid);
            kt = (int)(key & 63u);
            const double piv = readlane_f64(diag_r, kt);
            double ip = 1.0 / piv;
            ip = (piv > thr) ? ip : 0.0;
            invP = ip;
            if (tid == 0) { kk_own = kt; ip_own = ip; }
            if (tid == kt) {
                #pragma unroll
                for (int j = 0; j < MEQ; ++j) SrowA[j] = Sreg[j];
            }
        }
        for (int t = 0; t < MEQ; t += 2) {
            P3_STEP(t,     SrowA, SrowB);
            P3_STEP(t + 1, SrowB, SrowA);
        }

        // ---- P4: backward solve, column-sweep (no wave_sum ladders) ----
        // rhs_tau = fy[kt_tau] * invP_tau, gathered once via bpermute.
        double fyp;
        {
            DU a; a.d = fy_r; DU r;
            const int ad = kk_own << 2;
            r.i[0] = __builtin_amdgcn_ds_bpermute(ad, a.i[0]);
            r.i[1] = __builtin_amdgcn_ds_bpermute(ad, a.i[1]);
            fyp = r.d;
        }
        const double rhs = fyp * ip_own;            // 0 for dropped / extra lanes
        // prefetch LmT[t] = Lm[row][kt_t] into dead Sreg (40 indep. reads)
        #pragma unroll
        for (int t = 0; t < MEQ; ++t) {
            const int kts = __builtin_amdgcn_readlane(kk_own, t);
            Sreg[t] = Sl[row * SS + kts];
        }
        // descending sweep: resid_tau converges to x_tau (later-step updates
        // at lanes tau<=t are exact zeros since eliminated lanes stored Lm=0)
        double resid = rhs;
        #pragma unroll
        for (int t = MEQ - 1; t >= 0; --t) {
            const double xt = readlane_f64(resid, t);
            resid -= Sreg[t] * xt;
        }
        // scatter step-indexed x back to row indexing (pivots are a bijection)
        double X_r;
        {
            DU a; a.d = resid; DU r;
            const int ad = kk_own << 2;
            r.i[0] = __builtin_amdgcn_ds_permute(ad, a.i[0]);
            r.i[1] = __builtin_amdgcn_ds_permute(ad, a.i[1]);
            X_r = r.d;
        }
        if (tid < MEQ) Xl[tid] = X_r;               // stage dy for atdy matvec

        // ---- P5: dx/ds/dz, ratio test (DPP min), updates ----
        double ad0 = 0.0, ad1 = 0.0, ad2 = 0.0, ad3 = 0.0;
        #pragma unroll
        for (int j = 0; j < MEQ; j += 4) {
            ad0 += Ald[(j + 0) * SA + tid] * Xl[j + 0];
            ad1 += Ald[(j + 1) * SA + tid] * Xl[j + 1];
            ad2 += Ald[(j + 2) * SA + tid] * Xl[j + 2];
            ad3 += Ald[(j + 3) * SA + tid] * Xl[j + 3];
        }
        const double atdy = (ad0 + ad1) + (ad2 + ad3);
        const double dx = d_r * (rx - atdy);
        const double ds = dx - rs;                   // -rs + dx
        const double dz = rc - (z_r / s_r) * dx;
        double r = 1.0e300;
        if (ds < 0.0) r = -s_r / ds;
        if (dz < 0.0) r = fmin(r, -z_r / dz);
        r = wave_min_f64(r);
        const double alpha = fmin(1.0, FTB_C * r);
        x_r += alpha * dx;
        s_r += alpha * ds;
        z_r += alpha * dz;
        y_r += alpha * X_r;                          // lanes>=40: junk, never read
        if (tid < MEQ) yl[tid] = y_r;                // stage y for next aty
        __syncthreads();                             // Sl(Lm)/Xl/yl settle
    }

    out[b * NXV + tid] = (float)x_r;
}

extern "C" void kernel_launch(void* const* d_in, const int* in_sizes, int n_in,
                              void* d_out, int out_size, void* d_ws, size_t ws_size,
                              hipStream_t stream) {
    const float* puzzles = (const float*)d_in[0];
    const float* A       = (const float*)d_in[1];   // declared f64, delivered f32
    const float* logz0   = (const float*)d_in[2];
    // d_in[3] = Q (zeros, structural), d_in[4] = G (-I, structural)
    const float* u       = (const float*)d_in[5];
    float* out = (float*)d_out;

    const int n_batch = in_sizes[0] / NXV;   // 1024
    qp_ipm_kernel<<<n_batch, 64, 0, stream>>>(puzzles, A, logz0, u, out);
}

// Round 2
// 969.802 us; speedup vs baseline: 1.2872x; 1.1624x over previous
//
#include <hip/hip_runtime.h>
#include <math.h>

// QPLayer: batched primal-dual IPM, Q=0, G=-I (LP). f64 inputs DELIVERED AS F32
// (established round 8). Schur complement S = A diag(s/z) A^T (40x40), solved
// with COMPLETE-DIAGONAL-PIVOTED LDL^T (greedy max pivot; load-bearing), lane i
// owns row i of S in registers.
// ROUND 20 (remove the last LDS roundtrip from P3's serial spine):
//  * S stays SYMMETRIC under the congruent updates, so the per-lane column
//    value col_i = S[i][kt] is lane i's OWN Sreg[kt]. Extract it with a fused
//    cndmask pass keyed on the pipelined next-pivot index ktn (4 independent
//    10-deep select chains, combined by exact +0.0 adds) instead of staging
//    lane ktn's row through LDS with 40 exec-masked ds_writes.
//  * The j-loop's wave-uniform broadcast source Srow[j] == colreg_j, so one
//    lane-parallel ds_write (Srow[tid] = colreg, 2 lanes/bank = free)
//    replaces the 40-write staging; Srow double-buffer removed.
//  * diag/argmax selector chain is now register+DPP only (no LDS latency on
//    the loop-carried spine); argmax/rcp overlap the rank-1 FMAs.
//  * P2 k-loop unroll-2 to coax paired ds_read_b128 (halves P2 DS issue).
// P4 column-sweep, DPP ladders, packed-key argmax unchanged (verified R19).
// One wave per batch element; 1024 waves = 4/CU (structural, grid-limited).
// LDS 36.1 KB. 4 syncthreads/iter (single-wave: ordering guards only).

#define NXV   64
#define MEQ   40
#define NITER 25
#define SIGMA_C 0.1
#define FTB_C   0.99
#define SA 65    // LDS row stride for A (doubles)
#define SS 41    // LDS row stride for S staging / Lm store (doubles)
#define PIV_DROP_REL 1e-12

union DU { double d; int i[2]; unsigned u[2]; };

__device__ __forceinline__ double readlane_f64(double v, int lane) {
    DU a; a.d = v; DU r;
    r.i[0] = __builtin_amdgcn_readlane(a.i[0], lane);
    r.i[1] = __builtin_amdgcn_readlane(a.i[1], lane);
    return r.d;
}

// DPP wave64 reduction ladders (verified bit-exact rounds 16/17).
template<int CTRL>
__device__ __forceinline__ double dpp_add_step(double v) {
    DU a; a.d = v; DU b;
    b.i[0] = __builtin_amdgcn_update_dpp(0, a.i[0], CTRL, 0xf, 0xf, true);
    b.i[1] = __builtin_amdgcn_update_dpp(0, a.i[1], CTRL, 0xf, 0xf, true);
    return v + b.d;
}
__device__ __forceinline__ double wave_sum_f64(double v) {
    v = dpp_add_step<0x111>(v); v = dpp_add_step<0x112>(v);
    v = dpp_add_step<0x114>(v); v = dpp_add_step<0x118>(v);
    v = dpp_add_step<0x142>(v); v = dpp_add_step<0x143>(v);
    return readlane_f64(v, 63);
}
template<int CTRL>
__device__ __forceinline__ double dpp_min_step(double v) {   // identity +inf
    DU a; a.d = v; DU b;
    b.i[0] = __builtin_amdgcn_update_dpp(0x00000000, a.i[0], CTRL, 0xf, 0xf, false);
    b.i[1] = __builtin_amdgcn_update_dpp(0x7ff00000, a.i[1], CTRL, 0xf, 0xf, false);
    return fmin(v, b.d);
}
__device__ __forceinline__ double wave_min_f64(double v) {
    v = dpp_min_step<0x111>(v); v = dpp_min_step<0x112>(v);
    v = dpp_min_step<0x114>(v); v = dpp_min_step<0x118>(v);
    v = dpp_min_step<0x142>(v); v = dpp_min_step<0x143>(v);
    return readlane_f64(v, 63);
}
template<int CTRL>
__device__ __forceinline__ double dpp_max_step(double v) {   // identity -inf
    DU a; a.d = v; DU b;
    b.i[0] = __builtin_amdgcn_update_dpp(0x00000000, a.i[0], CTRL, 0xf, 0xf, false);
    b.i[1] = __builtin_amdgcn_update_dpp((int)0xfff00000u, a.i[1], CTRL, 0xf, 0xf, false);
    return fmax(v, b.d);
}
__device__ __forceinline__ double wave_max_f64(double v) {
    v = dpp_max_step<0x111>(v); v = dpp_max_step<0x112>(v);
    v = dpp_max_step<0x114>(v); v = dpp_max_step<0x118>(v);
    v = dpp_max_step<0x142>(v); v = dpp_max_step<0x143>(v);
    return readlane_f64(v, 63);
}
template<int CTRL>
__device__ __forceinline__ unsigned dpp_maxu_step(unsigned v) {
    unsigned m = (unsigned)__builtin_amdgcn_update_dpp(0, (int)v, CTRL, 0xf, 0xf, true);
    return v > m ? v : m;
}
__device__ __forceinline__ unsigned wave_max_u32(unsigned v) {
    v = dpp_maxu_step<0x111>(v); v = dpp_maxu_step<0x112>(v);
    v = dpp_maxu_step<0x114>(v); v = dpp_maxu_step<0x118>(v);
    v = dpp_maxu_step<0x142>(v); v = dpp_maxu_step<0x143>(v);
    return (unsigned)__builtin_amdgcn_readlane((int)v, 63);
}

__global__ __launch_bounds__(64, 1)
void qp_ipm_kernel(const float* __restrict__ puzzles,
                   const float* __restrict__ Af,
                   const float* __restrict__ lzf,
                   const float* __restrict__ uf,
                   float* __restrict__ out)
{
    __shared__ double Ald[MEQ * SA];                 // 20,800 B
    __shared__ double Sl[MEQ * SS];                  // 13,120 B (S stage, then Lm)
    __shared__ double dl[NXV];                       //    512 B
    __shared__ double vl[NXV];                       //    512 B
    __shared__ __align__(16) double Srow[NXV];       //    512 B (column broadcast)
    __shared__ double yl[MEQ];                       //    320 B
    __shared__ double Xl[MEQ];                       //    320 B

    const int tid = threadIdx.x;       // 0..63, one wave
    const int b   = blockIdx.x;
    const int row = (tid < MEQ) ? tid : 0;

    for (int e = tid; e < MEQ * NXV; e += 64)
        Ald[(e >> 6) * SA + (e & 63)] = (double)Af[e];
    dl[tid] = exp((double)lzf[tid]);
    if (tid < MEQ) yl[tid] = 0.0;
    __syncthreads();
    double b0 = 0.0, b1 = 0.0, b2 = 0.0, b3 = 0.0;
    #pragma unroll
    for (int i = 0; i < NXV; i += 4) {
        b0 += Ald[row * SA + i + 0] * dl[i + 0];
        b1 += Ald[row * SA + i + 1] * dl[i + 1];
        b2 += Ald[row * SA + i + 2] * dl[i + 2];
        b3 += Ald[row * SA + i + 3] * dl[i + 3];
    }
    const double b_r = (b0 + b1) + (b2 + b3);

    const double u_i = (double)uf[tid];
    const double p_i = -(double)puzzles[b * NXV + tid];
    double x_r = 0.0, s_r = 1.0, z_r = 1.0, y_r = 0.0;

    for (int it = 0; it < NITER; ++it) {
        // ---- P1: residuals/scalings; broadcasts via uniform LDS reads ----
        double at0 = 0.0, at1 = 0.0, at2 = 0.0, at3 = 0.0;
        #pragma unroll
        for (int j = 0; j < MEQ; j += 4) {
            at0 += Ald[(j + 0) * SA + tid] * yl[j + 0];
            at1 += Ald[(j + 1) * SA + tid] * yl[j + 1];
            at2 += Ald[(j + 2) * SA + tid] * yl[j + 2];
            at3 += Ald[(j + 3) * SA + tid] * yl[j + 3];
        }
        const double aty = (at0 + at1) + (at2 + at3);
        const double rd = p_i + aty - z_r;          // Q=0, G^T z = -z
        const double rs = s_r - x_r - u_i;          // -x + s - u
        const double mu = wave_sum_f64(s_r * z_r) * (1.0 / 64.0);
        const double rc = (SIGMA_C * mu - z_r * s_r + z_r * rs) / s_r;
        const double rx = rc - rd;                  // rhs_x
        const double d_r = s_r / z_r;
        const double v_r = d_r * rx + x_r;          // fy = A v - b
        vl[tid] = v_r;                              // same-wave order: write->read ok
        dl[tid] = d_r;

        double f0 = 0.0, f1 = 0.0, f2 = 0.0, f3 = 0.0;
        #pragma unroll
        for (int i = 0; i < NXV; i += 4) {
            f0 += Ald[row * SA + i + 0] * vl[i + 0];
            f1 += Ald[row * SA + i + 1] * vl[i + 1];
            f2 += Ald[row * SA + i + 2] * vl[i + 2];
            f3 += Ald[row * SA + i + 3] * vl[i + 3];
        }
        double fy_r = (f0 + f1) + (f2 + f3) - b_r;
        __syncthreads();                            // barrier 0: dl visible

        // ---- P2: S = A diag(d) A^T, 4x4 lower tiles (lanes<55) -> LDS ----
        // Transposed copy also stored so the S row load is 40 straight reads.
        if (tid < 55) {
            int uu = tid, mb = 0;
            while (uu > mb) { uu -= (mb + 1); ++mb; }
            const int nb = uu;
            double a00=0,a01=0,a02=0,a03=0, a10=0,a11=0,a12=0,a13=0,
                   a20=0,a21=0,a22=0,a23=0, a30=0,a31=0,a32=0,a33=0;
            const double* Am = &Ald[(4 * mb) * SA];
            const double* An = &Ald[(4 * nb) * SA];
            #pragma unroll 2
            for (int k = 0; k < NXV; ++k) {
                const double dk = dl[k];
                const double r0 = Am[0*SA+k], r1 = Am[1*SA+k], r2 = Am[2*SA+k], r3 = Am[3*SA+k];
                const double c0 = An[0*SA+k]*dk, c1 = An[1*SA+k]*dk, c2 = An[2*SA+k]*dk, c3 = An[3*SA+k]*dk;
                a00 += r0*c0; a01 += r0*c1; a02 += r0*c2; a03 += r0*c3;
                a10 += r1*c0; a11 += r1*c1; a12 += r1*c2; a13 += r1*c3;
                a20 += r2*c0; a21 += r2*c1; a22 += r2*c2; a23 += r2*c3;
                a30 += r3*c0; a31 += r3*c1; a32 += r3*c2; a33 += r3*c3;
            }
            double* Sp = &Sl[(4 * mb) * SS + 4 * nb];
            Sp[0*SS+0]=a00; Sp[0*SS+1]=a01; Sp[0*SS+2]=a02; Sp[0*SS+3]=a03;
            Sp[1*SS+0]=a10; Sp[1*SS+1]=a11; Sp[1*SS+2]=a12; Sp[1*SS+3]=a13;
            Sp[2*SS+0]=a20; Sp[2*SS+1]=a21; Sp[2*SS+2]=a22; Sp[2*SS+3]=a23;
            Sp[3*SS+0]=a30; Sp[3*SS+1]=a31; Sp[3*SS+2]=a32; Sp[3*SS+3]=a33;
            if (mb != nb) {                         // transpose tile
                double* Sq = &Sl[(4 * nb) * SS + 4 * mb];
                Sq[0*SS+0]=a00; Sq[1*SS+0]=a01; Sq[2*SS+0]=a02; Sq[3*SS+0]=a03;
                Sq[0*SS+1]=a10; Sq[1*SS+1]=a11; Sq[2*SS+1]=a12; Sq[3*SS+1]=a13;
                Sq[0*SS+2]=a20; Sq[1*SS+2]=a21; Sq[2*SS+2]=a22; Sq[3*SS+2]=a23;
                Sq[0*SS+3]=a30; Sq[1*SS+3]=a31; Sq[2*SS+3]=a32; Sq[3*SS+3]=a33;
            }
        }
        __syncthreads();   // barrier 1: tiles visible

        // ---- load row tid of S into registers (full row now stored) ----
        double Sreg[MEQ];
        double diag_r;
        if (tid < MEQ) {
            #pragma unroll
            for (int j = 0; j < MEQ; ++j) Sreg[j] = Sl[tid * SS + j];
            diag_r = Sl[tid * SS + tid];
        } else {
            #pragma unroll
            for (int j = 0; j < MEQ; ++j) Sreg[j] = 0.0;
            diag_r = -1.0e308;
        }
        const double dg  = wave_max_f64(diag_r);
        const double thr = dg * PIV_DROP_REL;
        __syncthreads();   // barrier 2: Sl dead -> reuse as Lm store

        // ---- P3: pipelined greedy-max-pivot LDL^T, register-carried column ----
        double ip_own = 0.0;
        int    kk_own = tid;          // lanes >=40 self-push in the P4 scatter
        int    kt;  double invP, colreg;
        {   // prologue: select pivot 0; extract its column from OWN registers
            DU dd; dd.d = diag_r;
            const unsigned h  = dd.u[1];
            const unsigned mk = (h & 0x80000000u) ? ~h : (h | 0x80000000u);
            const unsigned key = wave_max_u32((mk & 0xFFFFFFC0u) | (unsigned)tid);
            kt = (int)(key & 63u);
            const double piv = readlane_f64(diag_r, kt);
            double ip = 1.0 / piv;
            ip = (piv > thr) ? ip : 0.0;
            invP = ip;
            if (tid == 0) { kk_own = kt; ip_own = ip; }
            double cA = 0.0, cB = 0.0, cC = 0.0, cD = 0.0;
            #pragma unroll
            for (int j = 0; j < 10; ++j) {           // 4 indep. select chains
                cA = (kt == j     ) ? Sreg[j     ] : cA;
                cB = (kt == j + 10) ? Sreg[j + 10] : cB;
                cC = (kt == j + 20) ? Sreg[j + 20] : cC;
                cD = (kt == j + 30) ? Sreg[j + 30] : cD;
            }
            colreg = (cA + cB) + (cC + cD);          // exactly one nonzero
            Srow[tid] = colreg;                      // broadcast stage (1 write)
        }
        for (int t = 0; t < MEQ; ++t) {
            // S[i][kt] carried in colreg: selector spine is register+DPP only
            const double Lm_ = (diag_r > -1.0e307 && tid != kt) ? colreg * invP : 0.0;
            if (tid < MEQ) Sl[t * SS + tid] = Lm_;   // multiplier -> dead LDS (P4)
            diag_r -= Lm_ * colreg;                  // selector maintenance
            if (tid == kt) diag_r = -1.0e308;        // eliminated
            const double fyk_ = readlane_f64(fy_r, kt);
            fy_r -= Lm_ * fyk_;                      // unit-L forward solve
            // next pivot selection (overlaps the rank-1 below)
            DU dd_; dd_.d = diag_r;
            const unsigned h_  = dd_.u[1];
            const unsigned mk_ = (h_ & 0x80000000u) ? ~h_ : (h_ | 0x80000000u);
            const unsigned key_ = wave_max_u32((mk_ & 0xFFFFFFC0u) | (unsigned)tid);
            const int ktn_ = (int)(key_ & 63u);
            const double pivn_ = readlane_f64(diag_r, ktn_);
            double ipn_ = 1.0 / pivn_;
            ipn_ = (pivn_ > thr) ? ipn_ : 0.0;       // drop noise pivots
            if (tid == t + 1 && tid < MEQ) { kk_own = ktn_; ip_own = ipn_; }
            // rank-1 (Srow[j] == colreg_j by symmetry; uniform broadcast reads)
            // + fused extraction of next column from own updated registers
            double cA = 0.0, cB = 0.0, cC = 0.0, cD = 0.0;
            #pragma unroll
            for (int j = 0; j < 10; ++j) {
                Sreg[j     ] -= Lm_ * Srow[j     ];  cA = (ktn_ == j     ) ? Sreg[j     ] : cA;
                Sreg[j + 10] -= Lm_ * Srow[j + 10];  cB = (ktn_ == j + 10) ? Sreg[j + 10] : cB;
                Sreg[j + 20] -= Lm_ * Srow[j + 20];  cC = (ktn_ == j + 20) ? Sreg[j + 20] : cC;
                Sreg[j + 30] -= Lm_ * Srow[j + 30];  cD = (ktn_ == j + 30) ? Sreg[j + 30] : cD;
            }
            colreg = (cA + cB) + (cC + cD);
            Srow[tid] = colreg;                      // stage for step t+1
            kt = ktn_; invP = ipn_;
        }

        // ---- P4: backward solve, column-sweep (no wave_sum ladders) ----
        // rhs_tau = fy[kt_tau] * invP_tau, gathered once via bpermute.
        double fyp;
        {
            DU a; a.d = fy_r; DU r;
            const int ad = kk_own << 2;
            r.i[0] = __builtin_amdgcn_ds_bpermute(ad, a.i[0]);
            r.i[1] = __builtin_amdgcn_ds_bpermute(ad, a.i[1]);
            fyp = r.d;
        }
        const double rhs = fyp * ip_own;            // 0 for dropped / extra lanes
        // prefetch LmT[t] = Lm[kt_t][row-step] into dead Sreg (indep. reads)
        #pragma unroll
        for (int t = 0; t < MEQ; ++t) {
            const int kts = __builtin_amdgcn_readlane(kk_own, t);
            Sreg[t] = Sl[row * SS + kts];
        }
        // descending sweep: resid_tau converges to x_tau
        double resid = rhs;
        #pragma unroll
        for (int t = MEQ - 1; t >= 0; --t) {
            const double xt = readlane_f64(resid, t);
            resid -= Sreg[t] * xt;
        }
        // scatter step-indexed x back to row indexing (pivots are a bijection)
        double X_r;
        {
            DU a; a.d = resid; DU r;
            const int ad = kk_own << 2;
            r.i[0] = __builtin_amdgcn_ds_permute(ad, a.i[0]);
            r.i[1] = __builtin_amdgcn_ds_permute(ad, a.i[1]);
            X_r = r.d;
        }
        if (tid < MEQ) Xl[tid] = X_r;               // stage dy for atdy matvec

        // ---- P5: dx/ds/dz, ratio test (DPP min), updates ----
        double ad0 = 0.0, ad1 = 0.0, ad2 = 0.0, ad3 = 0.0;
        #pragma unroll
        for (int j = 0; j < MEQ; j += 4) {
            ad0 += Ald[(j + 0) * SA + tid] * Xl[j + 0];
            ad1 += Ald[(j + 1) * SA + tid] * Xl[j + 1];
            ad2 += Ald[(j + 2) * SA + tid] * Xl[j + 2];
            ad3 += Ald[(j + 3) * SA + tid] * Xl[j + 3];
        }
        const double atdy = (ad0 + ad1) + (ad2 + ad3);
        const double dx = d_r * (rx - atdy);
        const double ds = dx - rs;                   // -rs + dx
        const double dz = rc - (z_r / s_r) * dx;
        double r = 1.0e300;
        if (ds < 0.0) r = -s_r / ds;
        if (dz < 0.0) r = fmin(r, -z_r / dz);
        r = wave_min_f64(r);
        const double alpha = fmin(1.0, FTB_C * r);
        x_r += alpha * dx;
        s_r += alpha * ds;
        z_r += alpha * dz;
        y_r += alpha * X_r;                          // lanes>=40: junk, never read
        if (tid < MEQ) yl[tid] = y_r;                // stage y for next aty
        __syncthreads();                             // Sl(Lm)/Xl/yl settle
    }

    out[b * NXV + tid] = (float)x_r;
}

extern "C" void kernel_launch(void* const* d_in, const int* in_sizes, int n_in,
                              void* d_out, int out_size, void* d_ws, size_t ws_size,
                              hipStream_t stream) {
    const float* puzzles = (const float*)d_in[0];
    const float* A       = (const float*)d_in[1];   // declared f64, delivered f32
    const float* logz0   = (const float*)d_in[2];
    // d_in[3] = Q (zeros, structural), d_in[4] = G (-I, structural)
    const float* u       = (const float*)d_in[5];
    float* out = (float*)d_out;

    const int n_batch = in_sizes[0] / NXV;   // 1024
    qp_ipm_kernel<<<n_batch, 64, 0, stream>>>(puzzles, A, logz0, u, out);
}

// Round 3
// 761.445 us; speedup vs baseline: 1.6394x; 1.2736x over previous
//
#include <hip/hip_runtime.h>
#include <math.h>

// QPLayer: batched primal-dual IPM, Q=0, G=-I (LP). f64 inputs DELIVERED AS F32
// (established round 8). Schur complement S = A diag(s/z) A^T (40x40), solved
// with COMPLETE-DIAGONAL-PIVOTED LDL^T (greedy max pivot; load-bearing), lane i
// owns row i of S in registers.
// ROUND 21 (kill the cndmask select chain in P3):
//  * Sreg held as ext_vector chunks (16+16+8 f64). The wave-uniform runtime
//    extraction colreg = Sreg[ktn] compiles to M0-indexed v_movrels (dynamic
//    extractelement on a VGPR-resident vector) instead of a 40 s_cmp + 80
//    v_cndmask chain (~240 cy/step of VALU issue ON the spine). All other
//    accesses remain compile-time-static (chunk-split loops) so the vectors
//    stay in registers (rule-#20 scratch trap avoided).
//  * argmax ladder tail: after 4 row_shr DPP steps lanes 15/31/47/63 hold the
//    row maxima; 4 v_readlane + 3 s_max_u32 replace the row_bcast15/31 DPP
//    steps (shorter latency; result lands in the SGPR we need for readlane /
//    divide anyway). Bit-exact same argmax (same packed keys).
//  * Everything else unchanged from R20 (register-carried column, LDS Srow
//    broadcast for the rank-1, pipelined argmax/divide, P4 column-sweep).
// One wave per batch element; 1024 waves = 4/CU (structural, grid-limited).
// LDS 36.1 KB. 4 syncthreads/iter (single-wave: ordering guards only).

#define NXV   64
#define MEQ   40
#define NITER 25
#define SIGMA_C 0.1
#define FTB_C   0.99
#define SA 65    // LDS row stride for A (doubles)
#define SS 41    // LDS row stride for S staging / Lm store (doubles)
#define PIV_DROP_REL 1e-12

typedef double f64x16 __attribute__((ext_vector_type(16)));
typedef double f64x8  __attribute__((ext_vector_type(8)));

union DU { double d; int i[2]; unsigned u[2]; };

__device__ __forceinline__ double readlane_f64(double v, int lane) {
    DU a; a.d = v; DU r;
    r.i[0] = __builtin_amdgcn_readlane(a.i[0], lane);
    r.i[1] = __builtin_amdgcn_readlane(a.i[1], lane);
    return r.d;
}

// DPP wave64 reduction ladders (verified bit-exact rounds 16/17).
template<int CTRL>
__device__ __forceinline__ double dpp_add_step(double v) {
    DU a; a.d = v; DU b;
    b.i[0] = __builtin_amdgcn_update_dpp(0, a.i[0], CTRL, 0xf, 0xf, true);
    b.i[1] = __builtin_amdgcn_update_dpp(0, a.i[1], CTRL, 0xf, 0xf, true);
    return v + b.d;
}
__device__ __forceinline__ double wave_sum_f64(double v) {
    v = dpp_add_step<0x111>(v); v = dpp_add_step<0x112>(v);
    v = dpp_add_step<0x114>(v); v = dpp_add_step<0x118>(v);
    v = dpp_add_step<0x142>(v); v = dpp_add_step<0x143>(v);
    return readlane_f64(v, 63);
}
template<int CTRL>
__device__ __forceinline__ double dpp_min_step(double v) {   // identity +inf
    DU a; a.d = v; DU b;
    b.i[0] = __builtin_amdgcn_update_dpp(0x00000000, a.i[0], CTRL, 0xf, 0xf, false);
    b.i[1] = __builtin_amdgcn_update_dpp(0x7ff00000, a.i[1], CTRL, 0xf, 0xf, false);
    return fmin(v, b.d);
}
__device__ __forceinline__ double wave_min_f64(double v) {
    v = dpp_min_step<0x111>(v); v = dpp_min_step<0x112>(v);
    v = dpp_min_step<0x114>(v); v = dpp_min_step<0x118>(v);
    v = dpp_min_step<0x142>(v); v = dpp_min_step<0x143>(v);
    return readlane_f64(v, 63);
}
template<int CTRL>
__device__ __forceinline__ double dpp_max_step(double v) {   // identity -inf
    DU a; a.d = v; DU b;
    b.i[0] = __builtin_amdgcn_update_dpp(0x00000000, a.i[0], CTRL, 0xf, 0xf, false);
    b.i[1] = __builtin_amdgcn_update_dpp((int)0xfff00000u, a.i[1], CTRL, 0xf, 0xf, false);
    return fmax(v, b.d);
}
__device__ __forceinline__ double wave_max_f64(double v) {
    v = dpp_max_step<0x111>(v); v = dpp_max_step<0x112>(v);
    v = dpp_max_step<0x114>(v); v = dpp_max_step<0x118>(v);
    v = dpp_max_step<0x142>(v); v = dpp_max_step<0x143>(v);
    return readlane_f64(v, 63);
}
template<int CTRL>
__device__ __forceinline__ unsigned dpp_maxu_step(unsigned v) {
    unsigned m = (unsigned)__builtin_amdgcn_update_dpp(0, (int)v, CTRL, 0xf, 0xf, true);
    return v > m ? v : m;
}
// 4 row_shr steps leave row maxima in lanes 15/31/47/63; combine via
// readlane + s_max_u32 (shorter than row_bcast15/31 DPP; result in SGPR).
__device__ __forceinline__ unsigned wave_max_u32(unsigned v) {
    v = dpp_maxu_step<0x111>(v); v = dpp_maxu_step<0x112>(v);
    v = dpp_maxu_step<0x114>(v); v = dpp_maxu_step<0x118>(v);
    const unsigned a = (unsigned)__builtin_amdgcn_readlane((int)v, 15);
    const unsigned b = (unsigned)__builtin_amdgcn_readlane((int)v, 31);
    const unsigned c = (unsigned)__builtin_amdgcn_readlane((int)v, 47);
    const unsigned d = (unsigned)__builtin_amdgcn_readlane((int)v, 63);
    const unsigned ab = a > b ? a : b;
    const unsigned cd = c > d ? c : d;
    return ab > cd ? ab : cd;
}

__global__ __launch_bounds__(64, 1)
void qp_ipm_kernel(const float* __restrict__ puzzles,
                   const float* __restrict__ Af,
                   const float* __restrict__ lzf,
                   const float* __restrict__ uf,
                   float* __restrict__ out)
{
    __shared__ double Ald[MEQ * SA];                 // 20,800 B
    __shared__ double Sl[MEQ * SS];                  // 13,120 B (S stage, then Lm)
    __shared__ double dl[NXV];                       //    512 B
    __shared__ double vl[NXV];                       //    512 B
    __shared__ __align__(16) double Srow[NXV];       //    512 B (column broadcast)
    __shared__ double yl[MEQ];                       //    320 B
    __shared__ double Xl[MEQ];                       //    320 B

    const int tid = threadIdx.x;       // 0..63, one wave
    const int b   = blockIdx.x;
    const int row = (tid < MEQ) ? tid : 0;

    for (int e = tid; e < MEQ * NXV; e += 64)
        Ald[(e >> 6) * SA + (e & 63)] = (double)Af[e];
    dl[tid] = exp((double)lzf[tid]);
    if (tid < MEQ) yl[tid] = 0.0;
    __syncthreads();
    double b0 = 0.0, b1 = 0.0, b2 = 0.0, b3 = 0.0;
    #pragma unroll
    for (int i = 0; i < NXV; i += 4) {
        b0 += Ald[row * SA + i + 0] * dl[i + 0];
        b1 += Ald[row * SA + i + 1] * dl[i + 1];
        b2 += Ald[row * SA + i + 2] * dl[i + 2];
        b3 += Ald[row * SA + i + 3] * dl[i + 3];
    }
    const double b_r = (b0 + b1) + (b2 + b3);

    const double u_i = (double)uf[tid];
    const double p_i = -(double)puzzles[b * NXV + tid];
    double x_r = 0.0, s_r = 1.0, z_r = 1.0, y_r = 0.0;

    for (int it = 0; it < NITER; ++it) {
        // ---- P1: residuals/scalings; broadcasts via uniform LDS reads ----
        double at0 = 0.0, at1 = 0.0, at2 = 0.0, at3 = 0.0;
        #pragma unroll
        for (int j = 0; j < MEQ; j += 4) {
            at0 += Ald[(j + 0) * SA + tid] * yl[j + 0];
            at1 += Ald[(j + 1) * SA + tid] * yl[j + 1];
            at2 += Ald[(j + 2) * SA + tid] * yl[j + 2];
            at3 += Ald[(j + 3) * SA + tid] * yl[j + 3];
        }
        const double aty = (at0 + at1) + (at2 + at3);
        const double rd = p_i + aty - z_r;          // Q=0, G^T z = -z
        const double rs = s_r - x_r - u_i;          // -x + s - u
        const double mu = wave_sum_f64(s_r * z_r) * (1.0 / 64.0);
        const double rc = (SIGMA_C * mu - z_r * s_r + z_r * rs) / s_r;
        const double rx = rc - rd;                  // rhs_x
        const double d_r = s_r / z_r;
        const double v_r = d_r * rx + x_r;          // fy = A v - b
        vl[tid] = v_r;                              // same-wave order: write->read ok
        dl[tid] = d_r;

        double f0 = 0.0, f1 = 0.0, f2 = 0.0, f3 = 0.0;
        #pragma unroll
        for (int i = 0; i < NXV; i += 4) {
            f0 += Ald[row * SA + i + 0] * vl[i + 0];
            f1 += Ald[row * SA + i + 1] * vl[i + 1];
            f2 += Ald[row * SA + i + 2] * vl[i + 2];
            f3 += Ald[row * SA + i + 3] * vl[i + 3];
        }
        double fy_r = (f0 + f1) + (f2 + f3) - b_r;
        __syncthreads();                            // barrier 0: dl visible

        // ---- P2: S = A diag(d) A^T, 4x4 lower tiles (lanes<55) -> LDS ----
        // Transposed copy also stored so the S row load is 40 straight reads.
        if (tid < 55) {
            int uu = tid, mb = 0;
            while (uu > mb) { uu -= (mb + 1); ++mb; }
            const int nb = uu;
            double a00=0,a01=0,a02=0,a03=0, a10=0,a11=0,a12=0,a13=0,
                   a20=0,a21=0,a22=0,a23=0, a30=0,a31=0,a32=0,a33=0;
            const double* Am = &Ald[(4 * mb) * SA];
            const double* An = &Ald[(4 * nb) * SA];
            #pragma unroll 2
            for (int k = 0; k < NXV; ++k) {
                const double dk = dl[k];
                const double r0 = Am[0*SA+k], r1 = Am[1*SA+k], r2 = Am[2*SA+k], r3 = Am[3*SA+k];
                const double c0 = An[0*SA+k]*dk, c1 = An[1*SA+k]*dk, c2 = An[2*SA+k]*dk, c3 = An[3*SA+k]*dk;
                a00 += r0*c0; a01 += r0*c1; a02 += r0*c2; a03 += r0*c3;
                a10 += r1*c0; a11 += r1*c1; a12 += r1*c2; a13 += r1*c3;
                a20 += r2*c0; a21 += r2*c1; a22 += r2*c2; a23 += r2*c3;
                a30 += r3*c0; a31 += r3*c1; a32 += r3*c2; a33 += r3*c3;
            }
            double* Sp = &Sl[(4 * mb) * SS + 4 * nb];
            Sp[0*SS+0]=a00; Sp[0*SS+1]=a01; Sp[0*SS+2]=a02; Sp[0*SS+3]=a03;
            Sp[1*SS+0]=a10; Sp[1*SS+1]=a11; Sp[1*SS+2]=a12; Sp[1*SS+3]=a13;
            Sp[2*SS+0]=a20; Sp[2*SS+1]=a21; Sp[2*SS+2]=a22; Sp[2*SS+3]=a23;
            Sp[3*SS+0]=a30; Sp[3*SS+1]=a31; Sp[3*SS+2]=a32; Sp[3*SS+3]=a33;
            if (mb != nb) {                         // transpose tile
                double* Sq = &Sl[(4 * nb) * SS + 4 * mb];
                Sq[0*SS+0]=a00; Sq[1*SS+0]=a01; Sq[2*SS+0]=a02; Sq[3*SS+0]=a03;
                Sq[0*SS+1]=a10; Sq[1*SS+1]=a11; Sq[2*SS+1]=a12; Sq[3*SS+1]=a13;
                Sq[0*SS+2]=a20; Sq[1*SS+2]=a21; Sq[2*SS+2]=a22; Sq[3*SS+2]=a23;
                Sq[0*SS+3]=a30; Sq[1*SS+3]=a31; Sq[2*SS+3]=a32; Sq[3*SS+3]=a33;
            }
        }
        __syncthreads();   // barrier 1: tiles visible

        // ---- load row tid of S into register chunks (16+16+8) ----
        f64x16 Sg0, Sg1; f64x8 Sg2;
        double diag_r;
        if (tid < MEQ) {
            #pragma unroll
            for (int j = 0; j < 16; ++j) Sg0[j] = Sl[tid * SS + j];
            #pragma unroll
            for (int j = 0; j < 16; ++j) Sg1[j] = Sl[tid * SS + 16 + j];
            #pragma unroll
            for (int j = 0; j < 8; ++j)  Sg2[j] = Sl[tid * SS + 32 + j];
            diag_r = Sl[tid * SS + tid];
        } else {
            #pragma unroll
            for (int j = 0; j < 16; ++j) { Sg0[j] = 0.0; Sg1[j] = 0.0; }
            #pragma unroll
            for (int j = 0; j < 8; ++j)  Sg2[j] = 0.0;
            diag_r = -1.0e308;
        }
        const double dg  = wave_max_f64(diag_r);
        const double thr = dg * PIV_DROP_REL;
        __syncthreads();   // barrier 2: Sl dead -> reuse as Lm store

        // ---- P3: pipelined greedy-max-pivot LDL^T, movrel column extract ----
        double ip_own = 0.0;
        int    kk_own = tid;          // lanes >=40 self-push in the P4 scatter
        int    kt;  double invP, colreg;
        {   // prologue: select pivot 0; extract its column from OWN registers
            DU dd; dd.d = diag_r;
            const unsigned h  = dd.u[1];
            const unsigned mk = (h & 0x80000000u) ? ~h : (h | 0x80000000u);
            const unsigned key = wave_max_u32((mk & 0xFFFFFFC0u) | (unsigned)tid);
            kt = (int)(key & 63u);
            const double piv = readlane_f64(diag_r, kt);
            double ip = 1.0 / piv;
            ip = (piv > thr) ? ip : 0.0;
            invP = ip;
            if (tid == 0) { kk_own = kt; ip_own = ip; }
            const double e0 = Sg0[kt & 15];          // M0-indexed movrels
            const double e1 = Sg1[(kt - 16) & 15];
            const double e2 = Sg2[(kt - 32) & 7];
            colreg = (kt < 16) ? e0 : ((kt < 32) ? e1 : e2);
            Srow[tid] = colreg;                      // broadcast stage (1 write)
        }
        for (int t = 0; t < MEQ; ++t) {
            // S[i][kt] carried in colreg: selector spine is register+DPP only
            const double Lm_ = (diag_r > -1.0e307 && tid != kt) ? colreg * invP : 0.0;
            if (tid < MEQ) Sl[t * SS + tid] = Lm_;   // multiplier -> dead LDS (P4)
            diag_r -= Lm_ * colreg;                  // selector maintenance
            if (tid == kt) diag_r = -1.0e308;        // eliminated
            const double fyk_ = readlane_f64(fy_r, kt);
            fy_r -= Lm_ * fyk_;                      // unit-L forward solve
            // next pivot selection (overlaps the rank-1 below)
            DU dd_; dd_.d = diag_r;
            const unsigned h_  = dd_.u[1];
            const unsigned mk_ = (h_ & 0x80000000u) ? ~h_ : (h_ | 0x80000000u);
            const unsigned key_ = wave_max_u32((mk_ & 0xFFFFFFC0u) | (unsigned)tid);
            const int ktn_ = (int)(key_ & 63u);
            const double pivn_ = readlane_f64(diag_r, ktn_);
            double ipn_ = 1.0 / pivn_;
            ipn_ = (pivn_ > thr) ? ipn_ : 0.0;       // drop noise pivots
            if (tid == t + 1 && tid < MEQ) { kk_own = ktn_; ip_own = ipn_; }
            // rank-1 (Srow[j] == colreg_j by symmetry; uniform broadcast reads)
            #pragma unroll
            for (int j = 0; j < 16; ++j) Sg0[j] -= Lm_ * Srow[j];
            #pragma unroll
            for (int j = 0; j < 16; ++j) Sg1[j] -= Lm_ * Srow[16 + j];
            #pragma unroll
            for (int j = 0; j < 8; ++j)  Sg2[j] -= Lm_ * Srow[32 + j];
            // extract next column from own updated registers (movrels)
            const double e0 = Sg0[ktn_ & 15];
            const double e1 = Sg1[(ktn_ - 16) & 15];
            const double e2 = Sg2[(ktn_ - 32) & 7];
            colreg = (ktn_ < 16) ? e0 : ((ktn_ < 32) ? e1 : e2);
            Srow[tid] = colreg;                      // stage for step t+1
            kt = ktn_; invP = ipn_;
        }

        // ---- P4: backward solve, column-sweep (no wave_sum ladders) ----
        // rhs_tau = fy[kt_tau] * invP_tau, gathered once via bpermute.
        double fyp;
        {
            DU a; a.d = fy_r; DU r;
            const int ad = kk_own << 2;
            r.i[0] = __builtin_amdgcn_ds_bpermute(ad, a.i[0]);
            r.i[1] = __builtin_amdgcn_ds_bpermute(ad, a.i[1]);
            fyp = r.d;
        }
        const double rhs = fyp * ip_own;            // 0 for dropped / extra lanes
        // prefetch LmT[t] = Lm[kt_t][step=row] into dead Sg chunks (indep reads)
        #pragma unroll
        for (int t = 0; t < 16; ++t) {
            const int kts = __builtin_amdgcn_readlane(kk_own, t);
            Sg0[t] = Sl[row * SS + kts];
        }
        #pragma unroll
        for (int t = 0; t < 16; ++t) {
            const int kts = __builtin_amdgcn_readlane(kk_own, 16 + t);
            Sg1[t] = Sl[row * SS + kts];
        }
        #pragma unroll
        for (int t = 0; t < 8; ++t) {
            const int kts = __builtin_amdgcn_readlane(kk_own, 32 + t);
            Sg2[t] = Sl[row * SS + kts];
        }
        // descending sweep: resid_tau converges to x_tau
        double resid = rhs;
        #pragma unroll
        for (int t = MEQ - 1; t >= 32; --t) {
            const double xt = readlane_f64(resid, t);
            resid -= Sg2[t - 32] * xt;
        }
        #pragma unroll
        for (int t = 31; t >= 16; --t) {
            const double xt = readlane_f64(resid, t);
            resid -= Sg1[t - 16] * xt;
        }
        #pragma unroll
        for (int t = 15; t >= 0; --t) {
            const double xt = readlane_f64(resid, t);
            resid -= Sg0[t] * xt;
        }
        // scatter step-indexed x back to row indexing (pivots are a bijection)
        double X_r;
        {
            DU a; a.d = resid; DU r;
            const int ad = kk_own << 2;
            r.i[0] = __builtin_amdgcn_ds_permute(ad, a.i[0]);
            r.i[1] = __builtin_amdgcn_ds_permute(ad, a.i[1]);
            X_r = r.d;
        }
        if (tid < MEQ) Xl[tid] = X_r;               // stage dy for atdy matvec

        // ---- P5: dx/ds/dz, ratio test (DPP min), updates ----
        double ad0 = 0.0, ad1 = 0.0, ad2 = 0.0, ad3 = 0.0;
        #pragma unroll
        for (int j = 0; j < MEQ; j += 4) {
            ad0 += Ald[(j + 0) * SA + tid] * Xl[j + 0];
            ad1 += Ald[(j + 1) * SA + tid] * Xl[j + 1];
            ad2 += Ald[(j + 2) * SA + tid] * Xl[j + 2];
            ad3 += Ald[(j + 3) * SA + tid] * Xl[j + 3];
        }
        const double atdy = (ad0 + ad1) + (ad2 + ad3);
        const double dx = d_r * (rx - atdy);
        const double ds = dx - rs;                   // -rs + dx
        const double dz = rc - (z_r / s_r) * dx;
        double r = 1.0e300;
        if (ds < 0.0) r = -s_r / ds;
        if (dz < 0.0) r = fmin(r, -z_r / dz);
        r = wave_min_f64(r);
        const double alpha = fmin(1.0, FTB_C * r);
        x_r += alpha * dx;
        s_r += alpha * ds;
        z_r += alpha * dz;
        y_r += alpha * X_r;                          // lanes>=40: junk, never read
        if (tid < MEQ) yl[tid] = y_r;                // stage y for next aty
        __syncthreads();                             // Sl(Lm)/Xl/yl settle
    }

    out[b * NXV + tid] = (float)x_r;
}

extern "C" void kernel_launch(void* const* d_in, const int* in_sizes, int n_in,
                              void* d_out, int out_size, void* d_ws, size_t ws_size,
                              hipStream_t stream) {
    const float* puzzles = (const float*)d_in[0];
    const float* A       = (const float*)d_in[1];   // declared f64, delivered f32
    const float* logz0   = (const float*)d_in[2];
    // d_in[3] = Q (zeros, structural), d_in[4] = G (-I, structural)
    const float* u       = (const float*)d_in[5];
    float* out = (float*)d_out;

    const int n_batch = in_sizes[0] / NXV;   // 1024
    qp_ipm_kernel<<<n_batch, 64, 0, stream>>>(puzzles, A, logz0, u, out);
}

// Round 5
// 709.266 us; speedup vs baseline: 1.7600x; 1.0736x over previous
//
#include <hip/hip_runtime.h>
#include <math.h>

// QPLayer: batched primal-dual IPM, Q=0, G=-I (LP). f64 inputs DELIVERED AS F32
// (established round 8). Schur complement S = A diag(s/z) A^T (40x40), solved
// with COMPLETE-DIAGONAL-PIVOTED LDL^T (greedy max pivot; load-bearing), lane i
// owns row i of S in registers.
// ROUND 23 == ROUND 22 RESUBMIT (bench infra failed twice; no kernel verdict).
// ROUND 22 (readlane-ization: LDS was being used as a lane->wave broadcast):
//  * Every wave-uniform broadcast that was staged through LDS (Srow for the
//    P3 rank-1, yl/vl/dl/Xl for the matvecs) is now a v_readlane_b64 pair:
//    value lands in an SGPR pair, feeds v_fma_f64 directly as the scalar
//    operand. No ds_write, no ds_read, no lgkmcnt wait on the spine.
//    ~1800 DS ops/iter removed. Bit-exact (readlane == what LDS returned).
//  * Srow/yl/vl/dl/Xl buffers deleted; barriers 0 and 3 deleted (nothing
//    staged). Sl stays: S-tile transpose staging + Lm store for P4's
//    per-lane gather (genuine data movement, not broadcast).
//  * Occupancy is grid-limited (1024 waves on 1024 SIMDs = 1 wave/SIMD), so
//    the extra SGPR/VGPR pressure is free; every removed stall is wall time.
// Everything else unchanged from R21 (movrel column extract, pipelined
// argmax/divide, packed-key argmax with readlane tail, P4 column-sweep).
// LDS 33.9 KB (Ald + Sl only).

#define NXV   64
#define MEQ   40
#define NITER 25
#define SIGMA_C 0.1
#define FTB_C   0.99
#define SA 65    // LDS row stride for A (doubles)
#define SS 41    // LDS row stride for S staging / Lm store (doubles)
#define PIV_DROP_REL 1e-12

typedef double f64x16 __attribute__((ext_vector_type(16)));
typedef double f64x8  __attribute__((ext_vector_type(8)));

union DU { double d; int i[2]; unsigned u[2]; };

__device__ __forceinline__ double readlane_f64(double v, int lane) {
    DU a; a.d = v; DU r;
    r.i[0] = __builtin_amdgcn_readlane(a.i[0], lane);
    r.i[1] = __builtin_amdgcn_readlane(a.i[1], lane);
    return r.d;
}

// DPP wave64 reduction ladders (verified bit-exact rounds 16/17).
template<int CTRL>
__device__ __forceinline__ double dpp_add_step(double v) {
    DU a; a.d = v; DU b;
    b.i[0] = __builtin_amdgcn_update_dpp(0, a.i[0], CTRL, 0xf, 0xf, true);
    b.i[1] = __builtin_amdgcn_update_dpp(0, a.i[1], CTRL, 0xf, 0xf, true);
    return v + b.d;
}
__device__ __forceinline__ double wave_sum_f64(double v) {
    v = dpp_add_step<0x111>(v); v = dpp_add_step<0x112>(v);
    v = dpp_add_step<0x114>(v); v = dpp_add_step<0x118>(v);
    v = dpp_add_step<0x142>(v); v = dpp_add_step<0x143>(v);
    return readlane_f64(v, 63);
}
template<int CTRL>
__device__ __forceinline__ double dpp_min_step(double v) {   // identity +inf
    DU a; a.d = v; DU b;
    b.i[0] = __builtin_amdgcn_update_dpp(0x00000000, a.i[0], CTRL, 0xf, 0xf, false);
    b.i[1] = __builtin_amdgcn_update_dpp(0x7ff00000, a.i[1], CTRL, 0xf, 0xf, false);
    return fmin(v, b.d);
}
__device__ __forceinline__ double wave_min_f64(double v) {
    v = dpp_min_step<0x111>(v); v = dpp_min_step<0x112>(v);
    v = dpp_min_step<0x114>(v); v = dpp_min_step<0x118>(v);
    v = dpp_min_step<0x142>(v); v = dpp_min_step<0x143>(v);
    return readlane_f64(v, 63);
}
template<int CTRL>
__device__ __forceinline__ double dpp_max_step(double v) {   // identity -inf
    DU a; a.d = v; DU b;
    b.i[0] = __builtin_amdgcn_update_dpp(0x00000000, a.i[0], CTRL, 0xf, 0xf, false);
    b.i[1] = __builtin_amdgcn_update_dpp((int)0xfff00000u, a.i[1], CTRL, 0xf, 0xf, false);
    return fmax(v, b.d);
}
__device__ __forceinline__ double wave_max_f64(double v) {
    v = dpp_max_step<0x111>(v); v = dpp_max_step<0x112>(v);
    v = dpp_max_step<0x114>(v); v = dpp_max_step<0x118>(v);
    v = dpp_max_step<0x142>(v); v = dpp_max_step<0x143>(v);
    return readlane_f64(v, 63);
}
template<int CTRL>
__device__ __forceinline__ unsigned dpp_maxu_step(unsigned v) {
    unsigned m = (unsigned)__builtin_amdgcn_update_dpp(0, (int)v, CTRL, 0xf, 0xf, true);
    return v > m ? v : m;
}
// 4 row_shr steps leave row maxima in lanes 15/31/47/63; combine via
// readlane + s_max (result lands in the SGPR we need anyway).
__device__ __forceinline__ unsigned wave_max_u32(unsigned v) {
    v = dpp_maxu_step<0x111>(v); v = dpp_maxu_step<0x112>(v);
    v = dpp_maxu_step<0x114>(v); v = dpp_maxu_step<0x118>(v);
    const unsigned a = (unsigned)__builtin_amdgcn_readlane((int)v, 15);
    const unsigned b = (unsigned)__builtin_amdgcn_readlane((int)v, 31);
    const unsigned c = (unsigned)__builtin_amdgcn_readlane((int)v, 47);
    const unsigned d = (unsigned)__builtin_amdgcn_readlane((int)v, 63);
    const unsigned ab = a > b ? a : b;
    const unsigned cd = c > d ? c : d;
    return ab > cd ? ab : cd;
}

__global__ __launch_bounds__(64, 1)
void qp_ipm_kernel(const float* __restrict__ puzzles,
                   const float* __restrict__ Af,
                   const float* __restrict__ lzf,
                   const float* __restrict__ uf,
                   float* __restrict__ out)
{
    __shared__ double Ald[MEQ * SA];                 // 20,800 B
    __shared__ double Sl[MEQ * SS];                  // 13,120 B (S stage, then Lm)

    const int tid = threadIdx.x;       // 0..63, one wave
    const int b   = blockIdx.x;
    const int row = (tid < MEQ) ? tid : 0;

    for (int e = tid; e < MEQ * NXV; e += 64)
        Ald[(e >> 6) * SA + (e & 63)] = (double)Af[e];
    const double ez = exp((double)lzf[tid]);
    __syncthreads();                                 // Ald visible (setup only)
    double b0 = 0.0, b1 = 0.0, b2 = 0.0, b3 = 0.0;
    #pragma unroll
    for (int i = 0; i < NXV; i += 4) {
        b0 += Ald[row * SA + i + 0] * readlane_f64(ez, i + 0);
        b1 += Ald[row * SA + i + 1] * readlane_f64(ez, i + 1);
        b2 += Ald[row * SA + i + 2] * readlane_f64(ez, i + 2);
        b3 += Ald[row * SA + i + 3] * readlane_f64(ez, i + 3);
    }
    const double b_r = (b0 + b1) + (b2 + b3);

    const double u_i = (double)uf[tid];
    const double p_i = -(double)puzzles[b * NXV + tid];
    double x_r = 0.0, s_r = 1.0, z_r = 1.0, y_r = 0.0;

    for (int it = 0; it < NITER; ++it) {
        // ---- P1: residuals/scalings; broadcasts via readlane (no LDS) ----
        double at0 = 0.0, at1 = 0.0, at2 = 0.0, at3 = 0.0;
        #pragma unroll
        for (int j = 0; j < MEQ; j += 4) {
            at0 += Ald[(j + 0) * SA + tid] * readlane_f64(y_r, j + 0);
            at1 += Ald[(j + 1) * SA + tid] * readlane_f64(y_r, j + 1);
            at2 += Ald[(j + 2) * SA + tid] * readlane_f64(y_r, j + 2);
            at3 += Ald[(j + 3) * SA + tid] * readlane_f64(y_r, j + 3);
        }
        const double aty = (at0 + at1) + (at2 + at3);
        const double rd = p_i + aty - z_r;          // Q=0, G^T z = -z
        const double rs = s_r - x_r - u_i;          // -x + s - u
        const double mu = wave_sum_f64(s_r * z_r) * (1.0 / 64.0);
        const double rc = (SIGMA_C * mu - z_r * s_r + z_r * rs) / s_r;
        const double rx = rc - rd;                  // rhs_x
        const double d_r = s_r / z_r;
        const double v_r = d_r * rx + x_r;          // fy = A v - b

        double f0 = 0.0, f1 = 0.0, f2 = 0.0, f3 = 0.0;
        #pragma unroll
        for (int i = 0; i < NXV; i += 4) {
            f0 += Ald[row * SA + i + 0] * readlane_f64(v_r, i + 0);
            f1 += Ald[row * SA + i + 1] * readlane_f64(v_r, i + 1);
            f2 += Ald[row * SA + i + 2] * readlane_f64(v_r, i + 2);
            f3 += Ald[row * SA + i + 3] * readlane_f64(v_r, i + 3);
        }
        double fy_r = (f0 + f1) + (f2 + f3) - b_r;

        // ---- P2: S = A diag(d) A^T, 4x4 lower tiles (lanes<55) -> LDS ----
        // d broadcast via readlane; transposed copy stored for straight loads.
        if (tid < 55) {
            int uu = tid, mb = 0;
            while (uu > mb) { uu -= (mb + 1); ++mb; }
            const int nb = uu;
            double a00=0,a01=0,a02=0,a03=0, a10=0,a11=0,a12=0,a13=0,
                   a20=0,a21=0,a22=0,a23=0, a30=0,a31=0,a32=0,a33=0;
            const double* Am = &Ald[(4 * mb) * SA];
            const double* An = &Ald[(4 * nb) * SA];
            #pragma unroll 2
            for (int k = 0; k < NXV; ++k) {
                const double dk = readlane_f64(d_r, k);
                const double r0 = Am[0*SA+k], r1 = Am[1*SA+k], r2 = Am[2*SA+k], r3 = Am[3*SA+k];
                const double c0 = An[0*SA+k]*dk, c1 = An[1*SA+k]*dk, c2 = An[2*SA+k]*dk, c3 = An[3*SA+k]*dk;
                a00 += r0*c0; a01 += r0*c1; a02 += r0*c2; a03 += r0*c3;
                a10 += r1*c0; a11 += r1*c1; a12 += r1*c2; a13 += r1*c3;
                a20 += r2*c0; a21 += r2*c1; a22 += r2*c2; a23 += r2*c3;
                a30 += r3*c0; a31 += r3*c1; a32 += r3*c2; a33 += r3*c3;
            }
            double* Sp = &Sl[(4 * mb) * SS + 4 * nb];
            Sp[0*SS+0]=a00; Sp[0*SS+1]=a01; Sp[0*SS+2]=a02; Sp[0*SS+3]=a03;
            Sp[1*SS+0]=a10; Sp[1*SS+1]=a11; Sp[1*SS+2]=a12; Sp[1*SS+3]=a13;
            Sp[2*SS+0]=a20; Sp[2*SS+1]=a21; Sp[2*SS+2]=a22; Sp[2*SS+3]=a23;
            Sp[3*SS+0]=a30; Sp[3*SS+1]=a31; Sp[3*SS+2]=a32; Sp[3*SS+3]=a33;
            if (mb != nb) {                         // transpose tile
                double* Sq = &Sl[(4 * nb) * SS + 4 * mb];
                Sq[0*SS+0]=a00; Sq[1*SS+0]=a01; Sq[2*SS+0]=a02; Sq[3*SS+0]=a03;
                Sq[0*SS+1]=a10; Sq[1*SS+1]=a11; Sq[2*SS+1]=a12; Sq[3*SS+1]=a13;
                Sq[0*SS+2]=a20; Sq[1*SS+2]=a21; Sq[2*SS+2]=a22; Sq[3*SS+2]=a23;
                Sq[0*SS+3]=a30; Sq[1*SS+3]=a31; Sq[2*SS+3]=a32; Sq[3*SS+3]=a33;
            }
        }
        __syncthreads();   // barrier 1: tiles visible

        // ---- load row tid of S into register chunks (16+16+8) ----
        f64x16 Sg0, Sg1; f64x8 Sg2;
        double diag_r;
        if (tid < MEQ) {
            #pragma unroll
            for (int j = 0; j < 16; ++j) Sg0[j] = Sl[tid * SS + j];
            #pragma unroll
            for (int j = 0; j < 16; ++j) Sg1[j] = Sl[tid * SS + 16 + j];
            #pragma unroll
            for (int j = 0; j < 8; ++j)  Sg2[j] = Sl[tid * SS + 32 + j];
            diag_r = Sl[tid * SS + tid];
        } else {
            #pragma unroll
            for (int j = 0; j < 16; ++j) { Sg0[j] = 0.0; Sg1[j] = 0.0; }
            #pragma unroll
            for (int j = 0; j < 8; ++j)  Sg2[j] = 0.0;
            diag_r = -1.0e308;
        }
        const double dg  = wave_max_f64(diag_r);
        const double thr = dg * PIV_DROP_REL;
        __syncthreads();   // barrier 2: Sl dead -> reuse as Lm store

        // ---- P3: pipelined greedy-max-pivot LDL^T; readlane broadcasts ----
        double ip_own = 0.0;
        int    kk_own = tid;          // lanes >=40 self-push in the P4 scatter
        int    kt;  double invP, colreg;
        {   // prologue: select pivot 0; extract its column from OWN registers
            DU dd; dd.d = diag_r;
            const unsigned h  = dd.u[1];
            const unsigned mk = (h & 0x80000000u) ? ~h : (h | 0x80000000u);
            const unsigned key = wave_max_u32((mk & 0xFFFFFFC0u) | (unsigned)tid);
            kt = (int)(key & 63u);
            const double piv = readlane_f64(diag_r, kt);
            double ip = 1.0 / piv;
            ip = (piv > thr) ? ip : 0.0;
            invP = ip;
            if (tid == 0) { kk_own = kt; ip_own = ip; }
            const double e0 = Sg0[kt & 15];          // M0-indexed movrels
            const double e1 = Sg1[(kt - 16) & 15];
            const double e2 = Sg2[(kt - 32) & 7];
            colreg = (kt < 16) ? e0 : ((kt < 32) ? e1 : e2);
        }
        for (int t = 0; t < MEQ; ++t) {
            // S[i][kt] carried in colreg: selector spine is register+DPP only
            const double Lm_ = (diag_r > -1.0e307 && tid != kt) ? colreg * invP : 0.0;
            if (tid < MEQ) Sl[t * SS + tid] = Lm_;   // multiplier -> dead LDS (P4)
            diag_r -= Lm_ * colreg;                  // selector maintenance
            if (tid == kt) diag_r = -1.0e308;        // eliminated
            const double fyk_ = readlane_f64(fy_r, kt);
            fy_r -= Lm_ * fyk_;                      // unit-L forward solve
            // next pivot selection (overlaps the rank-1 below)
            DU dd_; dd_.d = diag_r;
            const unsigned h_  = dd_.u[1];
            const unsigned mk_ = (h_ & 0x80000000u) ? ~h_ : (h_ | 0x80000000u);
            const unsigned key_ = wave_max_u32((mk_ & 0xFFFFFFC0u) | (unsigned)tid);
            const int ktn_ = (int)(key_ & 63u);
            const double pivn_ = readlane_f64(diag_r, ktn_);
            double ipn_ = 1.0 / pivn_;
            ipn_ = (pivn_ > thr) ? ipn_ : 0.0;       // drop noise pivots
            if (tid == t + 1 && tid < MEQ) { kk_own = ktn_; ip_own = ipn_; }
            // rank-1: column broadcast via readlane -> SGPR scalar operand
            #pragma unroll
            for (int j = 0; j < 16; ++j) Sg0[j] -= Lm_ * readlane_f64(colreg, j);
            #pragma unroll
            for (int j = 0; j < 16; ++j) Sg1[j] -= Lm_ * readlane_f64(colreg, 16 + j);
            #pragma unroll
            for (int j = 0; j < 8; ++j)  Sg2[j] -= Lm_ * readlane_f64(colreg, 32 + j);
            // extract next column from own updated registers (movrels)
            const double e0 = Sg0[ktn_ & 15];
            const double e1 = Sg1[(ktn_ - 16) & 15];
            const double e2 = Sg2[(ktn_ - 32) & 7];
            colreg = (ktn_ < 16) ? e0 : ((ktn_ < 32) ? e1 : e2);
            kt = ktn_; invP = ipn_;
        }

        // ---- P4: backward solve, column-sweep ----
        // rhs_tau = fy[kt_tau] * invP_tau, gathered once via bpermute.
        double fyp;
        {
            DU a; a.d = fy_r; DU r;
            const int ad = kk_own << 2;
            r.i[0] = __builtin_amdgcn_ds_bpermute(ad, a.i[0]);
            r.i[1] = __builtin_amdgcn_ds_bpermute(ad, a.i[1]);
            fyp = r.d;
        }
        const double rhs = fyp * ip_own;            // 0 for dropped / extra lanes
        // prefetch LmT[t] = Lm[step t][lane kt_t] into dead Sg chunks
        #pragma unroll
        for (int t = 0; t < 16; ++t) {
            const int kts = __builtin_amdgcn_readlane(kk_own, t);
            Sg0[t] = Sl[row * SS + kts];
        }
        #pragma unroll
        for (int t = 0; t < 16; ++t) {
            const int kts = __builtin_amdgcn_readlane(kk_own, 16 + t);
            Sg1[t] = Sl[row * SS + kts];
        }
        #pragma unroll
        for (int t = 0; t < 8; ++t) {
            const int kts = __builtin_amdgcn_readlane(kk_own, 32 + t);
            Sg2[t] = Sl[row * SS + kts];
        }
        // descending sweep: resid_tau converges to x_tau
        double resid = rhs;
        #pragma unroll
        for (int t = MEQ - 1; t >= 32; --t) {
            const double xt = readlane_f64(resid, t);
            resid -= Sg2[t - 32] * xt;
        }
        #pragma unroll
        for (int t = 31; t >= 16; --t) {
            const double xt = readlane_f64(resid, t);
            resid -= Sg1[t - 16] * xt;
        }
        #pragma unroll
        for (int t = 15; t >= 0; --t) {
            const double xt = readlane_f64(resid, t);
            resid -= Sg0[t] * xt;
        }
        // scatter step-indexed x back to row indexing (pivots are a bijection)
        double X_r;
        {
            DU a; a.d = resid; DU r;
            const int ad = kk_own << 2;
            r.i[0] = __builtin_amdgcn_ds_permute(ad, a.i[0]);
            r.i[1] = __builtin_amdgcn_ds_permute(ad, a.i[1]);
            X_r = r.d;
        }

        // ---- P5: dx/ds/dz, ratio test (DPP min), updates ----
        double ad0 = 0.0, ad1 = 0.0, ad2 = 0.0, ad3 = 0.0;
        #pragma unroll
        for (int j = 0; j < MEQ; j += 4) {
            ad0 += Ald[(j + 0) * SA + tid] * readlane_f64(X_r, j + 0);
            ad1 += Ald[(j + 1) * SA + tid] * readlane_f64(X_r, j + 1);
            ad2 += Ald[(j + 2) * SA + tid] * readlane_f64(X_r, j + 2);
            ad3 += Ald[(j + 3) * SA + tid] * readlane_f64(X_r, j + 3);
        }
        const double atdy = (ad0 + ad1) + (ad2 + ad3);
        const double dx = d_r * (rx - atdy);
        const double ds = dx - rs;                   // -rs + dx
        const double dz = rc - (z_r / s_r) * dx;
        double r = 1.0e300;
        if (ds < 0.0) r = -s_r / ds;
        if (dz < 0.0) r = fmin(r, -z_r / dz);
        r = wave_min_f64(r);
        const double alpha = fmin(1.0, FTB_C * r);
        x_r += alpha * dx;
        s_r += alpha * ds;
        z_r += alpha * dz;
        y_r += alpha * X_r;                          // lanes>=40: junk, never read
    }

    out[b * NXV + tid] = (float)x_r;
}

extern "C" void kernel_launch(void* const* d_in, const int* in_sizes, int n_in,
                              void* d_out, int out_size, void* d_ws, size_t ws_size,
                              hipStream_t stream) {
    const float* puzzles = (const float*)d_in[0];
    const float* A       = (const float*)d_in[1];   // declared f64, delivered f32
    const float* logz0   = (const float*)d_in[2];
    // d_in[3] = Q (zeros, structural), d_in[4] = G (-I, structural)
    const float* u       = (const float*)d_in[5];
    float* out = (float*)d_out;

    const int n_batch = in_sizes[0] / NXV;   // 1024
    qp_ipm_kernel<<<n_batch, 64, 0, stream>>>(puzzles, A, logz0, u, out);
}